// Round 1
// 658.849 us; speedup vs baseline: 1.0401x; 1.0401x over previous
//
#include <hip/hip_runtime.h>
#include <hip/hip_bf16.h>
#include <math.h>

#define NN 120000
#define NT 32
#define TPB 512
#define NBLK (NN / NT)   // 3750
#define BSEG 1024

typedef __attribute__((ext_vector_type(8))) short short8;
typedef __attribute__((ext_vector_type(16))) float floatx16;

// bf16 weight blob layout inside d_ws (element offsets)
#define OFF_A1_WV1 0
#define OFF_A1_WV2 4096
#define OFF_A1_WS  8192
#define OFF_A1_WG  90112
#define OFF_A1_WD  106496
#define OFF_A2_WV1 110592
#define OFF_N1_WV1 114688
#define OFF_N1_WV2 118784
#define OFF_N1_WS  122880
#define OFF_N1_WG  204800
#define OFF_N1_WD  221184
#define OFF_N2_WV1 225280
#define OFF_N2_WV2 229376
#define OFF_N2_WS  233472
#define OFF_N2_WG  315392
#define W_TOTAL    331776

// hardware bf16 convert (RNE, v_cvt_pk_bf16_f32 path) — replaces 4-op bit-twiddle
__device__ __forceinline__ unsigned short f2bf(float x) {
  __hip_bfloat16 b = __float2bfloat16(x);
  return __builtin_bit_cast(unsigned short, b);
}
__device__ __forceinline__ unsigned int f2bf2(float lo, float hi) {
  return (unsigned int)f2bf(lo) | ((unsigned int)f2bf(hi) << 16);
}
__device__ __forceinline__ float bf2f(unsigned short h) {
  return __uint_as_float(((unsigned int)h) << 16);
}
// unpack halves of a packed bf16 pair: 1 VALU op each
__device__ __forceinline__ float bflo(unsigned int u) { return __uint_as_float(u << 16); }
__device__ __forceinline__ float bfhi(unsigned int u) { return __uint_as_float(u & 0xffff0000u); }

struct P {
  const float *h_sca, *h_vec, *pos, *te;
  const float *a1_bg, *n1_bg, *n2_bg, *a2_Ws;
  const int *t, *bid;
  const unsigned short* wb;   // bf16 weight blob
  float *att, *w, *out;
};

// ---------------- weight fp32 -> bf16 conversion ----------------

struct CvtP { const float* src[15]; unsigned short* dst; };

__global__ __launch_bounds__(256) void cvt_kernel(CvtP c) {
  const int sizes[15] = {4096, 4096, 81920, 16384, 4096, 4096,
                         4096, 4096, 81920, 16384, 4096,
                         4096, 4096, 81920, 16384};
  int idx = blockIdx.x * 256 + threadIdx.x;
  if (idx >= W_TOTAL) return;
  int seg = 0, off = 0;
  while (idx - off >= sizes[seg]) { off += sizes[seg]; ++seg; }
  c.dst[idx] = f2bf(c.src[seg][idx - off]);
}

// ---------------- device ops (NT=32, TPB=512, 8 waves) ----------------
// LDS: scalars [i][k] stride 264 bf16 (single buffer, in-place big_gemm);
// vectors [(i*3+d)][c] stride 72 (two buffers A/B); sGN = union(sVN, sG).
// MFMA 32x32x16: A[m=lane&31][k=8*(lane>>5)+j], B[k][n=lane&31],
// C/D: col=lane&31, row=(reg&3)+8*(reg>>2)+4*(lane>>5)   [m74/m101]

// P1: stage h_sca+te -> sS (bf16, 2x b128/thread) and h_vec -> sV transposed.
// vec path: thread owns (node i, channels c0..c0+3): 3 aligned float4 loads,
// 6 pair-converts, 3 ds_write_b64 — no div/mod, no scalar LDS writes.
__device__ __forceinline__ void stage(const P& p, unsigned short* sS, unsigned short* sV,
                                      const float* te_row, int node0, int tid) {
  int i = tid >> 4, j = tid & 15;
  {
    int c0 = j * 16;
    const float4* src = (const float4*)&p.h_sca[(node0 + i) * 256 + c0];
    const float4* te4 = (const float4*)&te_row[c0];
    float4 a0 = src[0], b0 = te4[0];
    float4 a1 = src[1], b1 = te4[1];
    float4 a2 = src[2], b2 = te4[2];
    float4 a3 = src[3], b3 = te4[3];
    uint4 o0 = make_uint4(f2bf2(a0.x + b0.x, a0.y + b0.y), f2bf2(a0.z + b0.z, a0.w + b0.w),
                          f2bf2(a1.x + b1.x, a1.y + b1.y), f2bf2(a1.z + b1.z, a1.w + b1.w));
    uint4 o1 = make_uint4(f2bf2(a2.x + b2.x, a2.y + b2.y), f2bf2(a2.z + b2.z, a2.w + b2.w),
                          f2bf2(a3.x + b3.x, a3.y + b3.y), f2bf2(a3.z + b3.z, a3.w + b3.w));
    *(uint4*)&sS[i * 264 + c0] = o0;
    *(uint4*)&sS[i * 264 + c0 + 8] = o1;
  }
  {
    int c0 = j * 4;
    const float4* src = (const float4*)&p.h_vec[(node0 + i) * 192 + c0 * 3];
    float4 v0 = src[0], v1 = src[1], v2 = src[2];
    // f[3a+d] = (channel c0+a, dim d):
    // x: v0.x v0.w v1.z v2.y | y: v0.y v1.x v1.w v2.z | z: v0.z v1.y v2.x v2.w
    int b = (i * 3) * 72 + c0;
    *(uint2*)&sV[b]       = make_uint2(f2bf2(v0.x, v0.w), f2bf2(v1.z, v2.y));
    *(uint2*)&sV[b + 72]  = make_uint2(f2bf2(v0.y, v1.x), f2bf2(v1.w, v2.z));
    *(uint2*)&sV[b + 144] = make_uint2(f2bf2(v0.z, v1.y), f2bf2(v2.x, v2.w));
  }
}

// D[i][o] = sum_k X[i][k] W[o][k]; K=320=[VN(64)|sX(256)], O=256, one N-tile/wave.
// sDst MAY ALIAS sX/sVN: internal barrier before write-back. Caller barriers after.
__device__ __forceinline__ void big_gemm(const unsigned short* __restrict__ Wb,
                                         const unsigned short* sVN,
                                         const unsigned short* sX,
                                         unsigned short* sDst,
                                         int wid, int lane) {
  const int m = lane & 31, h = lane >> 5;
  const int n0 = wid * 32;
  const unsigned short* wrow = Wb + (n0 + m) * 320 + h * 8;
  floatx16 acc0 = {}, acc1 = {};
#pragma unroll
  for (int k = 0; k < 20; k += 2) {
    short8 a0, a1;
    if (k < 4)     a0 = *(const short8*)&sVN[m * 72 + k * 16 + h * 8];
    else           a0 = *(const short8*)&sX[m * 264 + (k - 4) * 16 + h * 8];
    if (k + 1 < 4) a1 = *(const short8*)&sVN[m * 72 + (k + 1) * 16 + h * 8];
    else           a1 = *(const short8*)&sX[m * 264 + (k - 3) * 16 + h * 8];
    short8 b0 = *(const short8*)&wrow[k * 16];
    short8 b1 = *(const short8*)&wrow[k * 16 + 16];
    acc0 = __builtin_amdgcn_mfma_f32_32x32x16_bf16(a0, b0, acc0, 0, 0, 0);
    acc1 = __builtin_amdgcn_mfma_f32_32x32x16_bf16(a1, b1, acc1, 0, 0, 0);
  }
  __syncthreads();                       // all reads of sX/sVN complete
#pragma unroll
  for (int r = 0; r < 16; ++r) {
    int row = (r & 3) + 8 * (r >> 2) + 4 * h;
    sDst[row * 264 + n0 + m] = f2bf(acc0[r] + acc1[r]);
  }
}

// gate[i][o] = sigmoid(sum_k X[i][k] Wg[o][k] + bg[o]); O=64 -> waves 0,1
__device__ __forceinline__ void gate_gemm(const unsigned short* __restrict__ Wg,
                                          const float* __restrict__ bg,
                                          const unsigned short* sX,
                                          unsigned short* sG, int wid, int lane) {
  const int m = lane & 31, h = lane >> 5;
  const int n0 = wid * 32;
  const unsigned short* wrow = Wg + (n0 + m) * 256 + h * 8;
  floatx16 acc0 = {}, acc1 = {};
#pragma unroll
  for (int k = 0; k < 16; k += 2) {
    short8 a0 = *(const short8*)&sX[m * 264 + k * 16 + h * 8];
    short8 a1 = *(const short8*)&sX[m * 264 + k * 16 + 16 + h * 8];
    short8 b0 = *(const short8*)&wrow[k * 16];
    short8 b1 = *(const short8*)&wrow[k * 16 + 16];
    acc0 = __builtin_amdgcn_mfma_f32_32x32x16_bf16(a0, b0, acc0, 0, 0, 0);
    acc1 = __builtin_amdgcn_mfma_f32_32x32x16_bf16(a1, b1, acc1, 0, 0, 0);
  }
  float bb = bg[n0 + m];
#pragma unroll
  for (int r = 0; r < 16; ++r) {
    int i = (r & 3) + 8 * (r >> 2) + 4 * h;
    float v = acc0[r] + acc1[r] + bb;
    sG[i * 64 + n0 + m] = f2bf(__builtin_amdgcn_rcpf(1.f + __expf(-v)));
  }
}

// D[nd][o] = sum_c src[nd][c] W[o][c]; nd=96 -> 3 M-tiles, o=64 -> 2 N-tiles.
// 6 tiles on waves 0..5; B-frags hoisted. Gating removed (done in gatemul phase).
__device__ __forceinline__ void vecmm(const unsigned short* __restrict__ Wb,
                                      const unsigned short* sSrc,
                                      unsigned short* sDst,
                                      int wid, int lane) {
  if (wid >= 6) return;
  const int m = lane & 31, h = lane >> 5;
  const int nd0 = (wid >> 1) * 32, o0 = (wid & 1) * 32;
  const unsigned short* wrow = Wb + (o0 + m) * 64 + h * 8;
  short8 b0 = *(const short8*)&wrow[0];
  short8 b1 = *(const short8*)&wrow[16];
  short8 b2 = *(const short8*)&wrow[32];
  short8 b3 = *(const short8*)&wrow[48];
  floatx16 acc = {};
#pragma unroll
  for (int k0 = 0; k0 < 64; k0 += 16) {
    short8 a = *(const short8*)&sSrc[(nd0 + m) * 72 + k0 + h * 8];
    short8 b = (k0 == 0) ? b0 : (k0 == 16) ? b1 : (k0 == 32) ? b2 : b3;
    acc = __builtin_amdgcn_mfma_f32_32x32x16_bf16(a, b, acc, 0, 0, 0);
  }
#pragma unroll
  for (int r = 0; r < 16; ++r) {
    int nd = nd0 + (r & 3) + 8 * (r >> 2) + 4 * h;
    sDst[nd * 72 + o0 + m] = f2bf(acc[r]);
  }
}

// 8-wide vnorm: threads 0..255, thread owns (node i, cols c0..c0+7).
// 3x ds_read_b128 + 1x ds_write_b128 (was 12 scalar reads + 4 scalar writes).
__device__ __forceinline__ void vnorm(const unsigned short* sV, unsigned short* sVN, int tid) {
  if (tid >= 256) return;
  int i = tid >> 3, c0 = (tid & 7) * 8;
  int b = (i * 3) * 72 + c0;
  short8 vx = *(const short8*)&sV[b];
  short8 vy = *(const short8*)&sV[b + 72];
  short8 vz = *(const short8*)&sV[b + 144];
  unsigned int o[4];
#pragma unroll
  for (int q = 0; q < 4; ++q) {
    float x0 = bf2f((unsigned short)vx[2 * q]),     y0 = bf2f((unsigned short)vy[2 * q]),     z0 = bf2f((unsigned short)vz[2 * q]);
    float x1 = bf2f((unsigned short)vx[2 * q + 1]), y1 = bf2f((unsigned short)vy[2 * q + 1]), z1 = bf2f((unsigned short)vz[2 * q + 1]);
    o[q] = f2bf2(sqrtf(x0 * x0 + y0 * y0 + z0 * z0), sqrtf(x1 * x1 + y1 * y1 + z1 * z1));
  }
  *(uint4*)&sVN[i * 72 + c0] = make_uint4(o[0], o[1], o[2], o[3]);
}

// elementwise gate fold: sVx[(i,d),c] *= sG[i][c]; threads 0..255, 8-wide.
// (replaces per-fragment gating inside vecmm's MFMA loop AND the *g in vn_lrelu)
__device__ __forceinline__ void gatemul(unsigned short* sVx, const unsigned short* sG, int tid) {
  if (tid >= 256) return;
  int i = tid >> 3, c0 = (tid & 7) * 8;
  short8 g = *(const short8*)&sG[i * 64 + c0];
  float gf[8];
#pragma unroll
  for (int j = 0; j < 8; ++j) gf[j] = bf2f((unsigned short)g[j]);
  int b = (i * 3) * 72 + c0;
#pragma unroll
  for (int d = 0; d < 3; ++d) {
    short8 v = *(const short8*)&sVx[b + d * 72];
    unsigned int o[4];
#pragma unroll
    for (int q = 0; q < 4; ++q)
      o[q] = f2bf2(bf2f((unsigned short)v[2 * q]) * gf[2 * q],
                   bf2f((unsigned short)v[2 * q + 1]) * gf[2 * q + 1]);
    *(uint4*)&sVx[b + d * 72] = make_uint4(o[0], o[1], o[2], o[3]);
  }
}

// VNLeakyReLU(x, d) -> sVx in place; x already gated (gatemul). threads 0..255, 8-wide.
__device__ __forceinline__ void vn_lrelu(unsigned short* sVx, const unsigned short* sVd, int tid) {
  if (tid >= 256) return;
  int i = tid >> 3, c0 = (tid & 7) * 8;
  int b = (i * 3) * 72 + c0;
  short8 x0 = *(const short8*)&sVx[b];
  short8 x1 = *(const short8*)&sVx[b + 72];
  short8 x2 = *(const short8*)&sVx[b + 144];
  short8 d0 = *(const short8*)&sVd[b];
  short8 d1 = *(const short8*)&sVd[b + 72];
  short8 d2 = *(const short8*)&sVd[b + 144];
  float rx[8], ry[8], rz[8];
#pragma unroll
  for (int j = 0; j < 8; ++j) {
    float a0 = bf2f((unsigned short)x0[j]), a1 = bf2f((unsigned short)x1[j]), a2 = bf2f((unsigned short)x2[j]);
    float e0 = bf2f((unsigned short)d0[j]), e1 = bf2f((unsigned short)d1[j]), e2 = bf2f((unsigned short)d2[j]);
    float dot = a0 * e0 + a1 * e1 + a2 * e2;
    float dsq = e0 * e0 + e1 * e1 + e2 * e2;
    float f = dot >= 0.f ? 0.f : 0.99f * dot * __builtin_amdgcn_rcpf(dsq + 1e-6f);
    rx[j] = a0 - f * e0; ry[j] = a1 - f * e1; rz[j] = a2 - f * e2;
  }
  unsigned int ox[4], oy[4], oz[4];
#pragma unroll
  for (int q = 0; q < 4; ++q) {
    ox[q] = f2bf2(rx[2 * q], rx[2 * q + 1]);
    oy[q] = f2bf2(ry[2 * q], ry[2 * q + 1]);
    oz[q] = f2bf2(rz[2 * q], rz[2 * q + 1]);
  }
  *(uint4*)&sVx[b]       = make_uint4(ox[0], ox[1], ox[2], ox[3]);
  *(uint4*)&sVx[b + 72]  = make_uint4(oy[0], oy[1], oy[2], oy[3]);
  *(uint4*)&sVx[b + 144] = make_uint4(oz[0], oz[1], oz[2], oz[3]);
}

// vectorized leaky-relu on scalar buffer, threads u..u+nthr-1 (b128 in/out)
__device__ __forceinline__ void lrelu_vec(unsigned short* sS, int u, int nthr) {
  for (int cc = u; cc < NT * 32; cc += nthr) {          // 32 chunks of 8 per row
    int i = cc >> 5, off = (cc & 31) * 8;
    short8 v = *(short8*)&sS[i * 264 + off];
    unsigned int o[4];
#pragma unroll
    for (int q = 0; q < 4; ++q) {
      float a = bf2f((unsigned short)v[2 * q]);
      float b = bf2f((unsigned short)v[2 * q + 1]);
      a = a >= 0.f ? a : 0.01f * a;
      b = b >= 0.f ? b : 0.01f * b;
      o[q] = f2bf2(a, b);
    }
    *(uint4*)&sS[i * 264 + off] = make_uint4(o[0], o[1], o[2], o[3]);
  }
}

__device__ __forceinline__ float* out_addr(float* out, int b, int f) {
  if (f < 256) return out + b * 256 + f;
  if (f < 448) return out + 1024 * 256 + b * 192 + (f - 256);
  return out + 1024 * 256 + 1024 * 192 + b * 3 + (f - 448);
}

// ---------------- kernel 1: attention branch -> att[n] ----------------

__global__ __launch_bounds__(TPB, 6) void att_kernel(P p) {
  __shared__ unsigned short sS[NT * 264];
  __shared__ unsigned short sVA[96 * 72], sVB[96 * 72];
  __shared__ unsigned short sGN[2304];           // union: sVN (2296) / sG (2048)
  unsigned short* sVN = sGN;
  unsigned short* sG = sGN;
  int tid = threadIdx.x, wid = tid >> 6, lane = tid & 63;
  int node0 = blockIdx.x * NT;
  const unsigned short* wb = p.wb;

  stage(p, sS, sVA, p.te + p.t[0] * 256, node0, tid); __syncthreads();        // P1
  vecmm(wb + OFF_A1_WV1, sVA, sVB, wid, lane); __syncthreads();               // P2: vi
  vnorm(sVB, sVN, tid); __syncthreads();                                      // P3
  big_gemm(wb + OFF_A1_WS, sVN, sS, sS, wid, lane); __syncthreads();          // P4: out_sca -> sS
  if (wid < 2) gate_gemm(wb + OFF_A1_WG, p.a1_bg, sS, sG, wid, lane);         // P5
  else vecmm(wb + OFF_A1_WV2, sVB, sVA, wid - 2, lane);                       //     out_vec (ungated)
  __syncthreads();
  gatemul(sVA, sG, tid); __syncthreads();                                     // P5.5: v *= g
  vecmm(wb + OFF_A1_WD, sVA, sVB, wid, lane); __syncthreads();                // P6: d = Wd(gv)
  vn_lrelu(sVA, sVB, tid); __syncthreads();                                   // P7: v -> sVA
  vecmm(wb + OFF_A2_WV1, sVA, sVB, wid, lane); __syncthreads();               // P8: vi2

  // P9: att[i] = sum_c a2_Ws[c]*||vi2[i][:,c]|| + sum_k a2_Ws[64+k]*lrelu(s[i][k])
  int i = tid >> 4, j = tid & 15;
  float part = 0.f;
  {
    int c0 = j * 4;
    uint2 wx = *(const uint2*)&sVB[(i * 3 + 0) * 72 + c0];
    uint2 wy = *(const uint2*)&sVB[(i * 3 + 1) * 72 + c0];
    uint2 wz = *(const uint2*)&sVB[(i * 3 + 2) * 72 + c0];
    float4 ws = *(const float4*)&p.a2_Ws[c0];
    float n0 = sqrtf(bflo(wx.x) * bflo(wx.x) + bflo(wy.x) * bflo(wy.x) + bflo(wz.x) * bflo(wz.x));
    float n1 = sqrtf(bfhi(wx.x) * bfhi(wx.x) + bfhi(wy.x) * bfhi(wy.x) + bfhi(wz.x) * bfhi(wz.x));
    float n2 = sqrtf(bflo(wx.y) * bflo(wx.y) + bflo(wy.y) * bflo(wy.y) + bflo(wz.y) * bflo(wz.y));
    float n3 = sqrtf(bfhi(wx.y) * bfhi(wx.y) + bfhi(wy.y) * bfhi(wy.y) + bfhi(wz.y) * bfhi(wz.y));
    part = fmaf(ws.x, n0, part);
    part = fmaf(ws.y, n1, part);
    part = fmaf(ws.z, n2, part);
    part = fmaf(ws.w, n3, part);
  }
  {
    int k0 = j * 16;
    short8 s0 = *(const short8*)&sS[i * 264 + k0];
    short8 s1 = *(const short8*)&sS[i * 264 + k0 + 8];
    const float4* wp = (const float4*)&p.a2_Ws[64 + k0];
#pragma unroll
    for (int q = 0; q < 4; ++q) {
      float4 w4 = wp[q];
      float vv[4];
#pragma unroll
      for (int e = 0; e < 4; ++e) {
        short raw = (q < 2) ? ((q == 0) ? s0[e] : s0[4 + e]) : ((q == 2) ? s1[e] : s1[4 + e]);
        float x = bf2f((unsigned short)raw);
        vv[e] = x >= 0.f ? x : 0.01f * x;
      }
      part = fmaf(w4.x, vv[0], part);
      part = fmaf(w4.y, vv[1], part);
      part = fmaf(w4.z, vv[2], part);
      part = fmaf(w4.w, vv[3], part);
    }
  }
  part += __shfl_down(part, 8, 16);
  part += __shfl_down(part, 4, 16);
  part += __shfl_down(part, 2, 16);
  part += __shfl_down(part, 1, 16);
  if (j == 0) p.att[node0 + i] = part;
}

// ---------------- kernel 2: segment softmax -> w[n] ----------------

__global__ __launch_bounds__(256) void softmax_kernel(const float* __restrict__ att,
                                                      const int* __restrict__ bid,
                                                      float* __restrict__ w) {
  __shared__ float red[256];
  __shared__ float s_m, s_z;
  int b = blockIdx.x, tid = threadIdx.x;
  int lo = 0, hi = NN;
  while (lo < hi) { int mid = (lo + hi) >> 1; if (bid[mid] < b) lo = mid + 1; else hi = mid; }
  int start = lo;
  hi = NN;
  while (lo < hi) { int mid = (lo + hi) >> 1; if (bid[mid] < b + 1) lo = mid + 1; else hi = mid; }
  int end = lo;

  float m = -1e30f;
  for (int i = start + tid; i < end; i += 256) m = fmaxf(m, att[i]);
  red[tid] = m; __syncthreads();
  for (int s = 128; s > 0; s >>= 1) { if (tid < s) red[tid] = fmaxf(red[tid], red[tid + s]); __syncthreads(); }
  if (tid == 0) s_m = red[0];
  __syncthreads();
  m = s_m;
  float z = 0.f;
  for (int i = start + tid; i < end; i += 256) z += __expf(att[i] - m);
  red[tid] = z; __syncthreads();
  for (int s = 128; s > 0; s >>= 1) { if (tid < s) red[tid] += red[tid + s]; __syncthreads(); }
  if (tid == 0) s_z = red[0];
  __syncthreads();
  float inv = 1.f / s_z;
  for (int i = start + tid; i < end; i += 256) w[i] = __expf(att[i] - m) * inv;
}

// ---------------- kernel 3: net branch + weighted segment sums ----------------

__global__ __launch_bounds__(TPB, 6) void net_kernel(P p) {
  __shared__ unsigned short sS[NT * 264];
  __shared__ unsigned short sVA[96 * 72], sVB[96 * 72];
  __shared__ unsigned short sGN[2304];
  __shared__ float s_w[NT];
  __shared__ float s_pos[NT * 3];
  __shared__ int s_bid[NT];
  unsigned short* sVN = sGN;
  unsigned short* sG = sGN;
  int tid = threadIdx.x, wid = tid >> 6, lane = tid & 63;
  int node0 = blockIdx.x * NT;
  const unsigned short* wb = p.wb;

  stage(p, sS, sVA, p.te + p.t[0] * 256, node0, tid); __syncthreads();        // P1
  vecmm(wb + OFF_N1_WV1, sVA, sVB, wid, lane);                                // P2: vi
  if (wid >= 6) {                                                             //     idle waves: fetch reduction data
    int u = tid - 384;                                                        // 0..127
    if (u < NT) { s_w[u] = p.w[node0 + u]; s_bid[u] = p.bid[node0 + u]; }
    for (int v = u; v < NT * 3; v += 128) s_pos[v] = p.pos[node0 * 3 + v];
  }
  __syncthreads();
  vnorm(sVB, sVN, tid); __syncthreads();                                      // P3
  big_gemm(wb + OFF_N1_WS, sVN, sS, sS, wid, lane); __syncthreads();          // P4: out_sca -> sS
  if (wid < 2) gate_gemm(wb + OFF_N1_WG, p.n1_bg, sS, sG, wid, lane);         // P5
  else vecmm(wb + OFF_N1_WV2, sVB, sVA, wid - 2, lane);
  __syncthreads();
  if (tid < 256) gatemul(sVA, sG, tid);                                       // P5.5: v *= g
  else lrelu_vec(sS, tid - 256, 256);                                         //       s2 = lrelu
  __syncthreads();
  vecmm(wb + OFF_N1_WD, sVA, sVB, wid, lane); __syncthreads();                // P6: d
  vn_lrelu(sVA, sVB, tid); __syncthreads();                                   // P7: v2 -> sVA
  vecmm(wb + OFF_N2_WV1, sVA, sVB, wid, lane); __syncthreads();               // P8: vi3
  vnorm(sVB, sVN, tid); __syncthreads();                                      // P9
  big_gemm(wb + OFF_N2_WS, sVN, sS, sS, wid, lane); __syncthreads();          // P10: fs -> sS
  if (wid < 2) gate_gemm(wb + OFF_N2_WG, p.n2_bg, sS, sG, wid, lane);         // P11
  else vecmm(wb + OFF_N2_WV2, sVB, sVA, wid - 2, lane);                       //  out_vec2 -> sVA
  __syncthreads();

  // P12: weighted segment reduction (gate2 folded into fv read)
  if (tid < 451) {
    int f = tid;
    float acc = 0.f;
    int cur = s_bid[0];
    int c = 0, d = 0;
    if (f >= 256 && f < 448) { int r = f - 256; c = r / 3; d = r - c * 3; }
    for (int i2 = 0; i2 < NT; ++i2) {
      int sg = s_bid[i2];
      if (sg != cur) { atomicAdd(out_addr(p.out, cur, f), acc); acc = 0.f; cur = sg; }
      float val;
      if (f < 256) val = bf2f(sS[i2 * 264 + f]);
      else if (f < 448)
        val = bf2f(sVA[(i2 * 3 + d) * 72 + c]) * bf2f(sG[i2 * 64 + c]);
      else val = s_pos[i2 * 3 + (f - 448)];
      acc = fmaf(s_w[i2], val, acc);
    }
    atomicAdd(out_addr(p.out, cur, f), acc);
  }
}

// ---------------- launch ----------------

extern "C" void kernel_launch(void* const* d_in, const int* in_sizes, int n_in,
                              void* d_out, int out_size, void* d_ws, size_t ws_size,
                              hipStream_t stream) {
  float* ws = (float*)d_ws;
  unsigned short* wb = (unsigned short*)(ws + 2 * NN);

  CvtP c;
  c.src[0]  = (const float*)d_in[4];   // a1_Wv1
  c.src[1]  = (const float*)d_in[5];   // a1_Wv2
  c.src[2]  = (const float*)d_in[6];   // a1_Ws
  c.src[3]  = (const float*)d_in[7];   // a1_Wg
  c.src[4]  = (const float*)d_in[9];   // a1_Wd
  c.src[5]  = (const float*)d_in[10];  // a2_Wv1
  c.src[6]  = (const float*)d_in[15];  // n1_Wv1
  c.src[7]  = (const float*)d_in[16];  // n1_Wv2
  c.src[8]  = (const float*)d_in[17];  // n1_Ws
  c.src[9]  = (const float*)d_in[18];  // n1_Wg
  c.src[10] = (const float*)d_in[20];  // n1_Wd
  c.src[11] = (const float*)d_in[21];  // n2_Wv1
  c.src[12] = (const float*)d_in[22];  // n2_Wv2
  c.src[13] = (const float*)d_in[23];  // n2_Ws
  c.src[14] = (const float*)d_in[24];  // n2_Wg
  c.dst = wb;

  P p;
  p.h_sca = (const float*)d_in[0];
  p.h_vec = (const float*)d_in[1];
  p.pos   = (const float*)d_in[2];
  p.te    = (const float*)d_in[3];
  p.a1_bg = (const float*)d_in[8];
  p.a2_Ws = (const float*)d_in[12];
  p.n1_bg = (const float*)d_in[19];
  p.n2_bg = (const float*)d_in[25];
  p.t   = (const int*)d_in[26];
  p.bid = (const int*)d_in[27];
  p.wb  = wb;
  p.att = ws;
  p.w   = ws + NN;
  p.out = (float*)d_out;

  hipMemsetAsync(d_out, 0, (size_t)out_size * sizeof(float), stream);
  cvt_kernel<<<(W_TOTAL + 255) / 256, 256, 0, stream>>>(c);
  att_kernel<<<NBLK, TPB, 0, stream>>>(p);
  softmax_kernel<<<BSEG, 256, 0, stream>>>(p.att, p.bid, p.w);
  net_kernel<<<NBLK, TPB, 0, stream>>>(p);
}